// Round 1
// baseline (740.977 us; speedup 1.0000x reference)
//
#include <hip/hip_runtime.h>

// Problem constants
#define B_    2
#define CE_   32
#define D_    12
#define H_    256
#define W_    256
#define HW_   (H_*W_)
#define HID_  256
#define NPD   8
#define NPH   25
#define NPW   25
#define NP_   (B_*NPD*NPH*NPW)   // 10000
#define PJ    1805               // 5*19*19
#define TM    16                 // patches per block in k_main

__device__ __forceinline__ void decompose_n(int n, int& b, int& pd, int& ph, int& pw) {
    b = n / (NPD*NPH*NPW);
    int r = n - b*(NPD*NPH*NPW);
    pd = r / (NPH*NPW);
    int r2 = r - pd*(NPH*NPW);
    ph = r2 / NPW;
    pw = r2 - ph*NPW;
}

// Kernel A: emb gather + GEMM1 (+ReLU) + per-patch center/valid
__global__ __launch_bounds__(256) void k_prep(
    const float* __restrict__ target, const float* __restrict__ pred,
    const float* __restrict__ W1, const float* __restrict__ b1,
    float* __restrict__ h_out, float* __restrict__ centers_out,
    int* __restrict__ valid_out)
{
    __shared__ float emb_s[8][CE_];
    const int tid = threadIdx.x;
    const int n0  = blockIdx.x * 8;
    const int m   = tid >> 5;      // patch within block [0,8)
    const int c   = tid & 31;      // channel [0,32)
    {
        int n = n0 + m, b, pd, ph, pw;
        decompose_n(n, b, pd, ph, pw);
        const int dc = 2 + pd, hc = 21 + 9*ph, wc = 21 + 9*pw;
        emb_s[m][c] = pred[(((size_t)b*CE_ + c)*D_ + dc)*HW_ + (size_t)hc*W_ + wc];
        if (c == 0) {
            const size_t tbase = (((size_t)b*4)*D_ + dc)*HW_ + (size_t)hc*W_ + wc;
            const float ctr = target[tbase];
            const float a1 = target[tbase + (size_t)1*D_*HW_];
            const float a2 = target[tbase + (size_t)2*D_*HW_];
            const float a3 = target[tbase + (size_t)3*D_*HW_];
            const float onb = fmaxf(fmaxf(1.f-a1, 1.f-a2), 1.f-a3);
            centers_out[n] = ctr;
            valid_out[n]   = ((ctr != 0.f) && (onb != 1.0f)) ? 1 : 0;
        }
    }
    __syncthreads();
    #pragma unroll
    for (int mm = 0; mm < 8; mm++) {
        float acc = b1[tid];
        #pragma unroll
        for (int cc = 0; cc < CE_; cc++)
            acc = fmaf(emb_s[mm][cc], W1[cc*HID_ + tid], acc);
        h_out[(size_t)(n0+mm)*HID_ + tid] = fmaxf(acc, 0.f);
    }
}

// Kernel B: GEMM2 + sigmoid + gt-side mask/pool + reduction
__global__ __launch_bounds__(256) void k_main(
    const float* __restrict__ target,
    const float* __restrict__ W2, const float* __restrict__ b2,
    const float* __restrict__ hg, const float* __restrict__ centers,
    const int* __restrict__ valid, double* __restrict__ accs)
{
    const int tid = threadIdx.x;
    const int n0  = blockIdx.x * TM;
    float num = 0.f, denp = 0.f, dent = 0.f;

    for (int j = tid; j < PJ; j += 256) {
        const int dz = j / 361;
        const int rj = j - dz*361;
        const int y  = rj / 19;
        const int x  = rj - y*19;

        float acc[TM];
        #pragma unroll
        for (int m = 0; m < TM; m++) acc[m] = 0.f;

        for (int k = 0; k < HID_; k += 4) {
            const float w0 = W2[(size_t)(k+0)*PJ + j];
            const float w1 = W2[(size_t)(k+1)*PJ + j];
            const float w2v = W2[(size_t)(k+2)*PJ + j];
            const float w3 = W2[(size_t)(k+3)*PJ + j];
            #pragma unroll
            for (int m = 0; m < TM; m++) {
                // wave-uniform address -> scalar loads (s_load_dwordx4)
                const float* hr = hg + (size_t)(n0+m)*HID_ + k;
                float a = acc[m];
                a = fmaf(hr[0], w0, a);
                a = fmaf(hr[1], w1, a);
                a = fmaf(hr[2], w2v, a);
                a = fmaf(hr[3], w3, a);
                acc[m] = a;
            }
        }

        const float bj = b2[j];
        #pragma unroll 1
        for (int m = 0; m < TM; m++) {
            const int n = n0 + m;
            if (!valid[n]) continue;          // uniform branch, skip whole patch
            int b, pd, ph, pw;
            decompose_n(n, b, pd, ph, pw);
            const float ctr = centers[n];
            const int d  = pd + dz;
            const int hh = 2 + 9*ph + 2*y;
            const int ww = 2 + 9*pw + 2*x;
            const size_t gidx = (((size_t)b*4)*D_ + d)*HW_ + (size_t)hh*W_ + ww;
            const float g00 = target[gidx],      g01 = target[gidx+1];
            const float g10 = target[gidx+W_],   g11 = target[gidx+W_+1];
            const bool ig = (g00==0.f) | (g01==0.f) | (g10==0.f) | (g11==0.f);
            if (!ig) {
                const float t = ((g00!=ctr) | (g01!=ctr) | (g10!=ctr) | (g11!=ctr)) ? 1.f : 0.f;
                const float logit = acc[m] + bj;
                const float pv = 1.f / (1.f + __expf(-logit));
                num  = fmaf(pv, t, num);
                denp = fmaf(pv, pv, denp);
                dent += t;                    // t^2 == t
            }
        }
    }

    // wave reduce (64 lanes)
    #pragma unroll
    for (int off = 32; off > 0; off >>= 1) {
        num  += __shfl_down(num,  off);
        denp += __shfl_down(denp, off);
        dent += __shfl_down(dent, off);
    }
    __shared__ float rn[4], rp[4], rt[4];
    const int wid = tid >> 6, lane = tid & 63;
    if (lane == 0) { rn[wid] = num; rp[wid] = denp; rt[wid] = dent; }
    __syncthreads();
    if (tid == 0) {
        const float n_ = rn[0]+rn[1]+rn[2]+rn[3];
        const float p_ = rp[0]+rp[1]+rp[2]+rp[3];
        const float t_ = rt[0]+rt[1]+rt[2]+rt[3];
        atomicAdd(&accs[0], (double)n_);
        atomicAdd(&accs[1], (double)p_);
        atomicAdd(&accs[2], (double)t_);
    }
}

__global__ void k_final(const double* __restrict__ accs, float* __restrict__ out) {
    const double num = accs[0];
    const double den = accs[1] + accs[2];
    const double d   = den > 1e-6 ? den : 1e-6;
    out[0] = (float)(-2.0 * num / d);
}

extern "C" void kernel_launch(void* const* d_in, const int* in_sizes, int n_in,
                              void* d_out, int out_size, void* d_ws, size_t ws_size,
                              hipStream_t stream) {
    const float* target = (const float*)d_in[0];
    const float* pred   = (const float*)d_in[1];
    const float* W1     = (const float*)d_in[2];
    const float* b1     = (const float*)d_in[3];
    const float* W2     = (const float*)d_in[4];
    const float* b2     = (const float*)d_in[5];
    float* out = (float*)d_out;

    char* ws = (char*)d_ws;
    double* accs   = (double*)ws;                                    // 3 doubles
    float*  h      = (float*)(ws + 64);                              // 10000*256 f32
    float*  ctrs   = (float*)(ws + 64 + (size_t)NP_*HID_*4);         // 10000 f32
    int*    valid  = (int*)  (ws + 64 + (size_t)NP_*HID_*4 + NP_*4); // 10000 i32

    hipMemsetAsync(d_ws, 0, 64, stream);
    hipLaunchKernelGGL(k_prep, dim3(NP_/8), dim3(256), 0, stream,
                       target, pred, W1, b1, h, ctrs, valid);
    hipLaunchKernelGGL(k_main, dim3(NP_/TM), dim3(256), 0, stream,
                       target, W2, b2, h, ctrs, valid, accs);
    hipLaunchKernelGGL(k_final, dim3(1), dim3(1), 0, stream, accs, out);
}

// Round 2
// 377.027 us; speedup vs baseline: 1.9653x; 1.9653x over previous
//
#include <hip/hip_runtime.h>

// Problem constants
#define B_    2
#define CE_   32
#define D_    12
#define H_    256
#define W_    256
#define HW_   (H_*W_)
#define HID_  256
#define NPD   8
#define NPH   25
#define NPW   25
#define NP_   (B_*NPD*NPH*NPW)   // 10000
#define PJ    1805               // 5*19*19
#define NTILE 113                // ceil(1805/16)
#define PJPAD (NTILE*16)         // 1808

typedef __attribute__((ext_vector_type(8))) short bf16x8;
typedef __attribute__((ext_vector_type(4))) float f32x4;

__device__ __forceinline__ void decompose_n(int n, int& b, int& pd, int& ph, int& pw) {
    b = n / (NPD*NPH*NPW);
    int r = n - b*(NPD*NPH*NPW);
    pd = r / (NPH*NPW);
    int r2 = r - pd*(NPH*NPW);
    ph = r2 / NPW;
    pw = r2 - ph*NPW;
}

__device__ __forceinline__ unsigned short f2bf(float f) {
    unsigned u = __float_as_uint(f);
    u += 0x7FFFu + ((u >> 16) & 1u);   // round-to-nearest-even
    return (unsigned short)(u >> 16);
}

// ---------------- W2 transpose + cast: W2[k][j] (f32) -> W2t[j][k] (bf16) ---
__global__ __launch_bounds__(256) void k_w2t(
    const float* __restrict__ W2, unsigned short* __restrict__ W2t)
{
    const int j = blockIdx.x;          // 0..1807
    const int k = threadIdx.x;         // 0..255
    float v = (j < PJ) ? W2[(size_t)k*PJ + j] : 0.f;
    W2t[(size_t)j*HID_ + k] = f2bf(v);
}

// ---------------- emb gather + GEMM1(+ReLU) -> bf16 h; centers/valid -------
__global__ __launch_bounds__(256) void k_prep(
    const float* __restrict__ target, const float* __restrict__ pred,
    const float* __restrict__ W1, const float* __restrict__ b1,
    unsigned short* __restrict__ hbf, float* __restrict__ centers_out,
    int* __restrict__ valid_out)
{
    __shared__ float emb_s[8][CE_];
    const int tid = threadIdx.x;
    const int n0  = blockIdx.x * 8;
    const int m   = tid & 7;           // patch within block
    const int c   = tid >> 3;          // channel 0..31
    {
        int n = n0 + m, b, pd, ph, pw;
        decompose_n(n, b, pd, ph, pw);
        const int dc = 2 + pd, hc = 21 + 9*ph, wc = 21 + 9*pw;
        emb_s[m][c] = pred[(((size_t)b*CE_ + c)*D_ + dc)*HW_ + (size_t)hc*W_ + wc];
        if (tid < 8) {   // m==tid, c==0 here; dc/hc/wc valid for patch n0+tid
            const size_t tbase = (((size_t)b*4)*D_ + dc)*HW_ + (size_t)hc*W_ + wc;
            const float ctr = target[tbase];
            const float a1 = target[tbase + (size_t)1*D_*HW_];
            const float a2 = target[tbase + (size_t)2*D_*HW_];
            const float a3 = target[tbase + (size_t)3*D_*HW_];
            const float onb = fmaxf(fmaxf(1.f-a1, 1.f-a2), 1.f-a3);
            centers_out[n] = ctr;
            valid_out[n]   = ((ctr != 0.f) && (onb != 1.0f)) ? 1 : 0;
        }
    }
    __syncthreads();
    float acc[8];
    const float bb = b1[tid];
    #pragma unroll
    for (int mm = 0; mm < 8; mm++) acc[mm] = bb;
    #pragma unroll
    for (int cc = 0; cc < CE_; cc += 4) {
        const float w0 = W1[(size_t)(cc+0)*HID_ + tid];
        const float w1 = W1[(size_t)(cc+1)*HID_ + tid];
        const float w2 = W1[(size_t)(cc+2)*HID_ + tid];
        const float w3 = W1[(size_t)(cc+3)*HID_ + tid];
        #pragma unroll
        for (int mm = 0; mm < 8; mm++) {
            const float4 e = *(const float4*)&emb_s[mm][cc];
            float a = acc[mm];
            a = fmaf(e.x, w0, a);
            a = fmaf(e.y, w1, a);
            a = fmaf(e.z, w2, a);
            a = fmaf(e.w, w3, a);
            acc[mm] = a;
        }
    }
    #pragma unroll
    for (int mm = 0; mm < 8; mm++)
        hbf[(size_t)(n0+mm)*HID_ + tid] = f2bf(fmaxf(acc[mm], 0.f));
}

// ---------------- MFMA GEMM2 + sigmoid + gt-pool + reduction ---------------
__global__ __launch_bounds__(256) void k_main(
    const float* __restrict__ target,
    const unsigned short* __restrict__ W2t, const float* __restrict__ b2,
    const unsigned short* __restrict__ hbf, const float* __restrict__ centers,
    const int* __restrict__ valid, double* __restrict__ accs)
{
    const int tid  = threadIdx.x;
    const int wave = tid >> 6;
    const int lane = tid & 63;
    const int quad = lane >> 4;        // 0..3
    const int l16  = lane & 15;        // 0..15
    const int m0   = blockIdx.x * 16;  // patch tile base

    __shared__ float cen_s[16];
    __shared__ int   val_s[16];
    __shared__ int   base_s[16];
    __shared__ float red_s[4][3];

    if (tid < 16) {
        const int n = m0 + tid;
        int b, pd, ph, pw;
        decompose_n(n, b, pd, ph, pw);
        cen_s[tid]  = centers[n];
        val_s[tid]  = valid[n];
        base_s[tid] = ((b*4*D_ + pd)*HW_) + (2 + 9*ph)*W_ + (2 + 9*pw);
    }
    __syncthreads();

    // A fragments: held in registers for the whole kernel.
    // lane holds A[m = l16][k = kk*32 + quad*8 + 0..7]
    bf16x8 afr[8];
    {
        const unsigned short* hrow = hbf + (size_t)(m0 + l16)*HID_ + quad*8;
        #pragma unroll
        for (int kk = 0; kk < 8; kk++)
            afr[kk] = *(const bf16x8*)(hrow + kk*32);
    }

    float num = 0.f, denp = 0.f, dent = 0.f;

    for (int nt = wave; nt < NTILE; nt += 4) {
        const int n0 = nt * 16;
        const int j  = n0 + l16;
        const bool jok = (j < PJ);

        // B fragments: lane holds B[k = kk*32 + quad*8 + 0..7][n = l16]
        const unsigned short* wrow = W2t + (size_t)(n0 + l16)*HID_ + quad*8;
        f32x4 acc = {0.f, 0.f, 0.f, 0.f};
        #pragma unroll
        for (int kk = 0; kk < 8; kk++) {
            const bf16x8 bfr = *(const bf16x8*)(wrow + kk*32);
            acc = __builtin_amdgcn_mfma_f32_16x16x32_bf16(afr[kk], bfr, acc, 0, 0, 0);
        }

        // epilogue: lane owns j = n0+l16, patches m0 + quad*4 + r
        int dz = 0, yy = 0, xx = 0;
        float bj = 0.f;
        if (jok) {
            dz = j / 361;
            const int rj = j - dz*361;
            yy = rj / 19;
            xx = rj - yy*19;
            bj = b2[j];
        }
        const int off_j = dz*HW_ + 2*yy*W_ + 2*xx;

        #pragma unroll
        for (int r = 0; r < 4; r++) {
            const int pl = quad*4 + r;
            if (jok && val_s[pl]) {
                const int base = base_s[pl] + off_j;
                const float ctr = cen_s[pl];
                const float g00 = target[base],      g01 = target[base+1];
                const float g10 = target[base+W_],   g11 = target[base+W_+1];
                const bool ig = (g00==0.f) | (g01==0.f) | (g10==0.f) | (g11==0.f);
                if (!ig) {
                    const float t = ((g00!=ctr) | (g01!=ctr) | (g10!=ctr) | (g11!=ctr)) ? 1.f : 0.f;
                    const float logit = acc[r] + bj;
                    const float pv = 1.f / (1.f + __expf(-logit));
                    num  = fmaf(pv, t, num);
                    denp = fmaf(pv, pv, denp);
                    dent += t;   // t^2 == t
                }
            }
        }
    }

    // wave reduce (64 lanes)
    #pragma unroll
    for (int off = 32; off > 0; off >>= 1) {
        num  += __shfl_down(num,  off);
        denp += __shfl_down(denp, off);
        dent += __shfl_down(dent, off);
    }
    if (lane == 0) { red_s[wave][0] = num; red_s[wave][1] = denp; red_s[wave][2] = dent; }
    __syncthreads();
    if (tid == 0) {
        const float n_ = red_s[0][0]+red_s[1][0]+red_s[2][0]+red_s[3][0];
        const float p_ = red_s[0][1]+red_s[1][1]+red_s[2][1]+red_s[3][1];
        const float t_ = red_s[0][2]+red_s[1][2]+red_s[2][2]+red_s[3][2];
        atomicAdd(&accs[0], (double)n_);
        atomicAdd(&accs[1], (double)p_);
        atomicAdd(&accs[2], (double)t_);
    }
}

__global__ void k_final(const double* __restrict__ accs, float* __restrict__ out) {
    const double num = accs[0];
    const double den = accs[1] + accs[2];
    const double d   = den > 1e-6 ? den : 1e-6;
    out[0] = (float)(-2.0 * num / d);
}

extern "C" void kernel_launch(void* const* d_in, const int* in_sizes, int n_in,
                              void* d_out, int out_size, void* d_ws, size_t ws_size,
                              hipStream_t stream) {
    const float* target = (const float*)d_in[0];
    const float* pred   = (const float*)d_in[1];
    const float* W1     = (const float*)d_in[2];
    const float* b1     = (const float*)d_in[3];
    const float* W2     = (const float*)d_in[4];
    const float* b2     = (const float*)d_in[5];
    float* out = (float*)d_out;

    char* ws = (char*)d_ws;
    double*         accs = (double*)ws;                       // 64 B
    unsigned short* hbf  = (unsigned short*)(ws + 64);        // 10000*256*2 = 5,120,000
    unsigned short* W2t  = (unsigned short*)(ws + 64 + 5120000);          // 1808*256*2 = 925,696
    float*          ctrs = (float*)(ws + 64 + 5120000 + 925696);          // 40,000
    int*            val  = (int*)  (ws + 64 + 5120000 + 925696 + 40000);  // 40,000

    hipMemsetAsync(d_ws, 0, 64, stream);
    hipLaunchKernelGGL(k_w2t, dim3(PJPAD), dim3(256), 0, stream, W2, W2t);
    hipLaunchKernelGGL(k_prep, dim3(NP_/8), dim3(256), 0, stream,
                       target, pred, W1, b1, hbf, ctrs, val);
    hipLaunchKernelGGL(k_main, dim3(NP_/16), dim3(256), 0, stream,
                       target, W2t, b2, hbf, ctrs, val, accs);
    hipLaunchKernelGGL(k_final, dim3(1), dim3(1), 0, stream, accs, out);
}